// Round 5
// baseline (418.286 us; speedup 1.0000x reference)
//
#include <hip/hip_runtime.h>
#include <math.h>

typedef _Float16 Hh;
typedef __attribute__((ext_vector_type(8))) _Float16 half8;
typedef __attribute__((ext_vector_type(4))) _Float16 half4;
typedef __attribute__((ext_vector_type(2))) _Float16 half2v;
typedef __attribute__((ext_vector_type(4))) float float4v;

#define B_ 2
#define H_ 16
#define N_ 2048
#define D_ 64
#define ND_ (N_*D_)
#define C1 0.04508422f   // (1/32)*log2(e); softmax in base-2 throughout

// ---------------------------------------------------------------------------
// K1: prep.
//  blocks [0,512):  premix q,k with W_pre -> f16 qb/kb [b][e][n][d]
//  blocks [512,768): transpose v -> f16 vt2, tile-blocked [be][jt][d][j&31]
// ---------------------------------------------------------------------------
__global__ __launch_bounds__(256) void prep_kernel(const float* __restrict__ q,
    const float* __restrict__ k, const float* __restrict__ v,
    const float* __restrict__ Wpre,
    Hh* __restrict__ qb, Hh* __restrict__ kb, Hh* __restrict__ vt2)
{
    int tid = threadIdx.x;
    int bid = blockIdx.x;
    if (bid < 512) {
        __shared__ float wsh[256];
        wsh[tid] = Wpre[tid];
        __syncthreads();
        int tensor = bid >> 8;
        int g = ((bid & 255) << 8) | tid;     // 0 .. 65535
        int b = g >> 15;
        int r = g & 32767;                    // (n,d4): n*16 + d4
        const float4* src = (const float4*)(tensor ? k : q);
        Hh* dst = tensor ? kb : qb;
        float4 x[16];
        #pragma unroll
        for (int f=0; f<16; f++) x[f] = src[(size_t)(b*16+f)*32768 + r];
        #pragma unroll
        for (int e=0; e<16; e++) {
            float4 a = make_float4(0.f,0.f,0.f,0.f);
            #pragma unroll
            for (int f=0; f<16; f++) {
                float wv = wsh[e*16+f];
                a.x += wv*x[f].x; a.y += wv*x[f].y; a.z += wv*x[f].z; a.w += wv*x[f].w;
            }
            half4 hv; hv[0]=(Hh)a.x; hv[1]=(Hh)a.y; hv[2]=(Hh)a.z; hv[3]=(Hh)a.w;
            *(half4*)(dst + (size_t)(b*16+e)*ND_ + (size_t)r*4) = hv;
        }
    } else {
        __shared__ Hh tile[64*48];            // [d][j], stride 48 halves
        int tb = bid - 512;                   // 0..255
        int be = tb >> 3;                     // 0..31
        int jtg = tb & 7;
        const float4* v4 = (const float4*)v;
        for (int u=0; u<8; u++) {
            int jt = jtg*8 + u;               // 0..63
            #pragma unroll
            for (int p=0; p<2; p++) {
                int j = p*16 + (tid>>4);
                int d4 = tid & 15;
                float4 val = v4[(size_t)be*32768 + (size_t)(jt*32+j)*16 + d4];
                tile[(d4*4+0)*48 + j] = (Hh)val.x;
                tile[(d4*4+1)*48 + j] = (Hh)val.y;
                tile[(d4*4+2)*48 + j] = (Hh)val.z;
                tile[(d4*4+3)*48 + j] = (Hh)val.w;
            }
            __syncthreads();
            {
                int d = tid >> 2;
                int jc = (tid & 3) * 8;
                half8 o;
                #pragma unroll
                for (int z=0; z<8; z++) o[z] = tile[d*48 + jc + z];
                *(half8*)(vt2 + ((size_t)(be*64) + jt)*2048 + (size_t)tid*8) = o;
            }
            __syncthreads();
        }
    }
}

// ---------------------------------------------------------------------------
// K2: denominators. LDS-free, barrier-free. 512 thr / 8 waves; wave w owns
// f = {2w, 2w+1}. i-tile 32, slab = 8 j-tiles of 32. All K/Q frags direct
// from global (L2). lacc_g[b,f,i] += sum_j exp2(C1*s) via unsafeAtomicAdd.
// ---------------------------------------------------------------------------
__global__ __launch_bounds__(512) void denom_kernel(const Hh* __restrict__ qb,
    const Hh* __restrict__ kb, float* __restrict__ lacc_g)
{
    int bid = blockIdx.x;
    int s = bid & 7;
    int idx = 127 - (bid >> 3);
    int b = idx & 1, it = idx >> 1;          // it 0..63
    if (8*s > it) return;
    int i0 = it * 32;
    int jt1 = (8*s + 7 < it) ? (8*s + 7) : it;

    int tid = threadIdx.x;
    int lane = tid & 63, w = tid >> 6;
    int qd = lane >> 4, c = lane & 15;
    int f0 = 2*w;

    half8 aq[2][2][2];
    #pragma unroll
    for (int fi=0; fi<2; fi++) {
        #pragma unroll
        for (int ig=0; ig<2; ig++) {
            const Hh* qr = qb + (size_t)((b*16+f0+fi)*N_ + i0 + ig*16 + c)*64 + qd*8;
            aq[fi][ig][0] = *(const half8*)qr;
            aq[fi][ig][1] = *(const half8*)(qr+32);
        }
    }
    float lacc[2][2][4];
    #pragma unroll
    for (int fi=0;fi<2;fi++) for (int ig=0;ig<2;ig++) for (int r=0;r<4;r++) lacc[fi][ig][r]=0.f;

    for (int jt = 8*s; jt <= jt1; jt++) {
        int j0 = jt*32;
        #pragma unroll
        for (int fi=0; fi<2; fi++) {
            #pragma unroll
            for (int jh=0; jh<2; jh++) {
                const Hh* kr = kb + (size_t)((b*16+f0+fi)*N_ + j0 + jh*16 + c)*64 + qd*8;
                half8 b0 = *(const half8*)kr;
                half8 b1 = *(const half8*)(kr+32);
                #pragma unroll
                for (int ig=0; ig<2; ig++) {
                    float4v sv = {0.f,0.f,0.f,0.f};
                    sv = __builtin_amdgcn_mfma_f32_16x16x32_f16(aq[fi][ig][0], b0, sv, 0,0,0);
                    sv = __builtin_amdgcn_mfma_f32_16x16x32_f16(aq[fi][ig][1], b1, sv, 0,0,0);
                    #pragma unroll
                    for (int r=0; r<4; r++) {
                        int i = i0 + ig*16 + qd*4 + r;
                        int j = j0 + jh*16 + c;
                        float ev = (j <= i) ? __builtin_amdgcn_exp2f(sv[r]*C1) : 0.f;
                        lacc[fi][ig][r] += ev;
                    }
                }
            }
        }
    }
    #pragma unroll
    for (int fi=0; fi<2; fi++) {
        #pragma unroll
        for (int ig=0; ig<2; ig++) {
            #pragma unroll
            for (int r=0; r<4; r++) {
                float vs = lacc[fi][ig][r];
                vs += __shfl_xor(vs, 1);
                vs += __shfl_xor(vs, 2);
                vs += __shfl_xor(vs, 4);
                vs += __shfl_xor(vs, 8);
                if (c == 0)
                    unsafeAtomicAdd(&lacc_g[(size_t)(b*16+f0+fi)*N_ + i0 + ig*16 + qd*4 + r], vs);
            }
        }
    }
}

// ---------------------------------------------------------------------------
// K3: main fused pass. 512 thr / 8 waves; i-tile 16, j-tile 32, slab = 16
// j-tiles (512 j). Wave w: scores f={2w,2w+1} (K direct from global);
// mix groups 4w..4w+3; PV e={2w,2w+1} as O^T = V^T * Pm^T (V direct from vt2).
// 2 barriers/iter: [mix] bar [PV(t) || scores(t+1)] bar. LDS 40 KB.
// ---------------------------------------------------------------------------
__global__ __launch_bounds__(512,4) void attend_kernel(const Hh* __restrict__ qb,
    const Hh* __restrict__ kb, const Hh* __restrict__ vt2,
    const float* __restrict__ lacc_g, const float* __restrict__ Wpost,
    float* __restrict__ out)
{
    __shared__ Hh Pbuf[512][20];    // [pt = il*32+jl][f]      20480 B
    __shared__ Hh Pm[32][16][20];   // [jl][il ^ ((jl&3)*4)][e] 20480 B

    int bid = blockIdx.x;
    int s = bid & 3;
    int idx = 255 - (bid >> 2);
    int b = idx & 1, it = idx >> 1;          // it 0..127
    int itj = it >> 1;                       // max 32-j tile index
    if (16*s > itj) return;
    int i0 = it * 16;
    int jt0 = 16*s;
    int jt1 = (16*s + 15 < itj) ? (16*s + 15) : itj;

    int tid = threadIdx.x;
    int lane = tid & 63, w = tid >> 6;
    int qd = lane >> 4, c = lane & 15;
    int f0 = 2*w;

    // Q A-frags (row i0+c) + log2-denominators for f0, f0+1
    half8 aq[2][2];
    float lgr[2][4];
    #pragma unroll
    for (int fi=0; fi<2; fi++) {
        const Hh* qr = qb + (size_t)((b*16+f0+fi)*N_ + i0 + c)*64 + qd*8;
        aq[fi][0] = *(const half8*)qr;
        aq[fi][1] = *(const half8*)(qr+32);
        #pragma unroll
        for (int r=0; r<4; r++)
            lgr[fi][r] = __builtin_amdgcn_logf(
                lacc_g[(size_t)(b*16+f0+fi)*N_ + i0 + qd*4 + r]);
    }
    // W_post A-frag (16x16x16): A[m=e=c][k=f=qd*4+z]
    half4 wf;
    #pragma unroll
    for (int z=0; z<4; z++) wf[z] = (Hh)Wpost[c*16 + qd*4 + z];

    float4v acc[2][4];
    #pragma unroll
    for (int el=0; el<2; el++) for (int md=0; md<4; md++)
        acc[el][md] = (float4v){0.f,0.f,0.f,0.f};

    // ---- scores for tile jt: K B-frags direct from global ----
    auto scores = [&](int jt) {
        int j0 = jt*32;
        float4v sv[2][2];
        #pragma unroll
        for (int fi=0; fi<2; fi++) {
            #pragma unroll
            for (int jh=0; jh<2; jh++) {
                const Hh* kr = kb + (size_t)((b*16+f0+fi)*N_ + j0 + jh*16 + c)*64 + qd*8;
                half8 b0 = *(const half8*)kr;
                half8 b1 = *(const half8*)(kr+32);
                float4v t = {0.f,0.f,0.f,0.f};
                t = __builtin_amdgcn_mfma_f32_16x16x32_f16(aq[fi][0], b0, t, 0,0,0);
                t = __builtin_amdgcn_mfma_f32_16x16x32_f16(aq[fi][1], b1, t, 0,0,0);
                sv[fi][jh] = t;
            }
        }
        #pragma unroll
        for (int jh=0; jh<2; jh++) {
            #pragma unroll
            for (int r=0; r<4; r++) {
                int i = i0 + qd*4 + r;
                int j = j0 + jh*16 + c;
                half2v hv;
                hv[0] = (Hh)((j <= i) ? __builtin_amdgcn_exp2f(sv[0][jh][r]*C1 - lgr[0][r]) : 0.f);
                hv[1] = (Hh)((j <= i) ? __builtin_amdgcn_exp2f(sv[1][jh][r]*C1 - lgr[1][r]) : 0.f);
                int pt = (qd*4+r)*32 + jh*16 + c;
                *(half2v*)&Pbuf[pt][f0] = hv;
            }
        }
    };

    scores(jt0);
    __syncthreads();

    for (int jt = jt0; jt <= jt1; jt++) {
        // ---- head mix: groups g = 4w..4w+3 (16 points each) ----
        #pragma unroll
        for (int gi=0; gi<4; gi++) {
            int g = w*4 + gi;
            int il = g >> 1, jh = g & 1;
            half4 bf = *(const half4*)&Pbuf[g*16 + c][qd*4];
            float4v cc = {0.f,0.f,0.f,0.f};
            cc = __builtin_amdgcn_mfma_f32_16x16x16f16(wf, bf, cc, 0,0,0);
            int jl = jh*16 + c;
            int ilp = il ^ ((jl&3)*4);
            half4 hv;
            #pragma unroll
            for (int r=0; r<4; r++) hv[r] = (Hh)cc[r];
            *(half4*)&Pm[jl][ilp][qd*4] = hv;   // slot e = qd*4+r
        }
        __syncthreads();
        // ---- PV(jt) (+ scores(jt+1) overlapped) ----
        {
            int j0 = jt*32;
            #pragma unroll
            for (int el=0; el<2; el++) {
                int e = f0 + el;
                half8 bb;
                #pragma unroll
                for (int z=0; z<8; z++)
                    bb[z] = Pm[qd*8+z][c ^ ((z&3)*4)][e];
                #pragma unroll
                for (int md=0; md<4; md++) {
                    const Hh* vr = vt2 + (size_t)((b*16+e)*64 + (j0>>5))*2048 + (md*16+c)*32 + qd*8;
                    half8 av = *(const half8*)vr;
                    acc[el][md] = __builtin_amdgcn_mfma_f32_16x16x32_f16(av, bb, acc[el][md], 0,0,0);
                }
            }
        }
        if (jt < jt1) scores(jt+1);
        __syncthreads();
    }

    // ---- atomic accumulate O^T fragments: C[m=d][n=i] ----
    #pragma unroll
    for (int el=0; el<2; el++) {
        int e = f0 + el;
        float* ob = out + (size_t)((b*16+e)*N_ + i0 + c)*64;
        #pragma unroll
        for (int md=0; md<4; md++) {
            #pragma unroll
            for (int r=0; r<4; r++)
                unsafeAtomicAdd(ob + md*16 + qd*4 + r, acc[el][md][r]);
        }
    }
}

extern "C" void kernel_launch(void* const* d_in, const int* in_sizes, int n_in,
                              void* d_out, int out_size, void* d_ws, size_t ws_size,
                              hipStream_t stream) {
    const float* q     = (const float*)d_in[0];
    const float* k     = (const float*)d_in[1];
    const float* v     = (const float*)d_in[2];
    const float* Wpre  = (const float*)d_in[3];
    const float* Wpost = (const float*)d_in[4];
    float* out = (float*)d_out;

    size_t tsz = (size_t)B_*H_*N_*D_;       // 4 Mi halves = 8 MB each
    Hh* qb = (Hh*)d_ws;
    Hh* kb = qb + tsz;
    Hh* vt2 = kb + tsz;
    float* lacc = (float*)(vt2 + tsz);      // 24 MB offset, 256 KB

    hipMemsetAsync(lacc, 0, (size_t)B_*H_*N_*sizeof(float), stream);
    hipMemsetAsync(out, 0, (size_t)out_size*sizeof(float), stream);
    prep_kernel<<<768, 256, 0, stream>>>(q, k, v, Wpre, qb, kb, vt2);
    denom_kernel<<<1024, 512, 0, stream>>>(qb, kb, lacc);
    attend_kernel<<<1024, 512, 0, stream>>>(qb, kb, vt2, lacc, Wpost, out);
}

// Round 6
// 268.554 us; speedup vs baseline: 1.5576x; 1.5576x over previous
//
#include <hip/hip_runtime.h>
#include <math.h>

typedef _Float16 Hh;
typedef __attribute__((ext_vector_type(8))) _Float16 half8;
typedef __attribute__((ext_vector_type(4))) _Float16 half4;
typedef __attribute__((ext_vector_type(4))) float float4v;

#define B_ 2
#define H_ 16
#define N_ 2048
#define D_ 64
#define ND_ (N_*D_)
#define C1 0.04508422f   // (1/32)*log2(e); softmax in base-2 throughout

// Ebuf: [j(32)][i(16)][f(16+4pad)]  j-stride 324, i-stride 20 halves
#define EB_JS 324
#define EB_IS 20
// Pm: [e(16)][i(16)][j(32+4pad)]    e-stride 580, i-stride 36 halves
#define PM_ES 580
#define PM_IS 36

// ---------------------------------------------------------------------------
// K1: prep.
//  blocks [0,512):  premix q,k with W_pre -> f16 qb/kb [b][e][n][d]
//  blocks [512,768): transpose v -> f16 vt2, tile-blocked [be][jt][d][j&31]
// ---------------------------------------------------------------------------
__global__ __launch_bounds__(256) void prep_kernel(const float* __restrict__ q,
    const float* __restrict__ k, const float* __restrict__ v,
    const float* __restrict__ Wpre,
    Hh* __restrict__ qb, Hh* __restrict__ kb, Hh* __restrict__ vt2)
{
    int tid = threadIdx.x;
    int bid = blockIdx.x;
    if (bid < 512) {
        __shared__ float wsh[256];
        wsh[tid] = Wpre[tid];
        __syncthreads();
        int tensor = bid >> 8;
        int g = ((bid & 255) << 8) | tid;     // 0 .. 65535
        int b = g >> 15;
        int r = g & 32767;                    // (n,d4): n*16 + d4
        const float4* src = (const float4*)(tensor ? k : q);
        Hh* dst = tensor ? kb : qb;
        float4 x[16];
        #pragma unroll
        for (int f=0; f<16; f++) x[f] = src[(size_t)(b*16+f)*32768 + r];
        #pragma unroll
        for (int e=0; e<16; e++) {
            float4 a = make_float4(0.f,0.f,0.f,0.f);
            #pragma unroll
            for (int f=0; f<16; f++) {
                float wv = wsh[e*16+f];
                a.x += wv*x[f].x; a.y += wv*x[f].y; a.z += wv*x[f].z; a.w += wv*x[f].w;
            }
            half4 hv; hv[0]=(Hh)a.x; hv[1]=(Hh)a.y; hv[2]=(Hh)a.z; hv[3]=(Hh)a.w;
            *(half4*)(dst + (size_t)(b*16+e)*ND_ + (size_t)r*4) = hv;
        }
    } else {
        __shared__ Hh tile[64*48];            // [d][j], stride 48 halves
        int tb = bid - 512;                   // 0..255
        int be = tb >> 3;                     // 0..31
        int jtg = tb & 7;
        const float4* v4 = (const float4*)v;
        for (int u=0; u<8; u++) {
            int jt = jtg*8 + u;               // 0..63
            #pragma unroll
            for (int p=0; p<2; p++) {
                int j = p*16 + (tid>>4);
                int d4 = tid & 15;
                float4 val = v4[(size_t)be*32768 + (size_t)(jt*32+j)*16 + d4];
                tile[(d4*4+0)*48 + j] = (Hh)val.x;
                tile[(d4*4+1)*48 + j] = (Hh)val.y;
                tile[(d4*4+2)*48 + j] = (Hh)val.z;
                tile[(d4*4+3)*48 + j] = (Hh)val.w;
            }
            __syncthreads();
            {
                int d = tid >> 2;
                int jc = (tid & 3) * 8;
                half8 o;
                #pragma unroll
                for (int z=0; z<8; z++) o[z] = tile[d*48 + jc + z];
                *(half8*)(vt2 + ((size_t)(be*64) + jt)*2048 + (size_t)tid*8) = o;
            }
            __syncthreads();
        }
    }
}

// ---------------------------------------------------------------------------
// K2: denominators. LDS-free, barrier-free, interleaved slabs (jt ≡ s mod 8).
// 512 thr / 8 waves; wave w owns f={2w,2w+1}; i-tile 32.
// ---------------------------------------------------------------------------
__global__ __launch_bounds__(512) void denom_kernel(const Hh* __restrict__ qb,
    const Hh* __restrict__ kb, float* __restrict__ lacc_g)
{
    int bid = blockIdx.x;
    int s = bid & 7;
    int idx = 127 - (bid >> 3);
    int b = idx & 1, it = idx >> 1;          // it 0..63
    if (s > it) return;

    int i0 = it * 32;
    int tid = threadIdx.x;
    int lane = tid & 63, w = tid >> 6;
    int qd = lane >> 4, c = lane & 15;
    int f0 = 2*w;

    half8 aq[2][2][2];
    #pragma unroll
    for (int fi=0; fi<2; fi++) {
        #pragma unroll
        for (int ig=0; ig<2; ig++) {
            const Hh* qr = qb + (size_t)((b*16+f0+fi)*N_ + i0 + ig*16 + c)*64 + qd*8;
            aq[fi][ig][0] = *(const half8*)qr;
            aq[fi][ig][1] = *(const half8*)(qr+32);
        }
    }
    float lacc[2][2][4];
    #pragma unroll
    for (int fi=0;fi<2;fi++) for (int ig=0;ig<2;ig++) for (int r=0;r<4;r++) lacc[fi][ig][r]=0.f;

    for (int jt = s; jt <= it; jt += 8) {
        int j0 = jt*32;
        #pragma unroll
        for (int fi=0; fi<2; fi++) {
            #pragma unroll
            for (int jh=0; jh<2; jh++) {
                const Hh* kr = kb + (size_t)((b*16+f0+fi)*N_ + j0 + jh*16 + c)*64 + qd*8;
                half8 b0 = *(const half8*)kr;
                half8 b1 = *(const half8*)(kr+32);
                #pragma unroll
                for (int ig=0; ig<2; ig++) {
                    float4v sv = {0.f,0.f,0.f,0.f};
                    sv = __builtin_amdgcn_mfma_f32_16x16x32_f16(aq[fi][ig][0], b0, sv, 0,0,0);
                    sv = __builtin_amdgcn_mfma_f32_16x16x32_f16(aq[fi][ig][1], b1, sv, 0,0,0);
                    #pragma unroll
                    for (int r=0; r<4; r++) {
                        int i = i0 + ig*16 + qd*4 + r;
                        int j = j0 + jh*16 + c;
                        float ev = (j <= i) ? __builtin_amdgcn_exp2f(sv[r]*C1) : 0.f;
                        lacc[fi][ig][r] += ev;
                    }
                }
            }
        }
    }
    #pragma unroll
    for (int fi=0; fi<2; fi++) {
        #pragma unroll
        for (int ig=0; ig<2; ig++) {
            #pragma unroll
            for (int r=0; r<4; r++) {
                float vs = lacc[fi][ig][r];
                vs += __shfl_xor(vs, 1);
                vs += __shfl_xor(vs, 2);
                vs += __shfl_xor(vs, 4);
                vs += __shfl_xor(vs, 8);
                if (c == 0)
                    unsafeAtomicAdd(&lacc_g[(size_t)(b*16+f0+fi)*N_ + i0 + ig*16 + qd*4 + r], vs);
            }
        }
    }
}

// ---------------------------------------------------------------------------
// K3: main fused pass. 512 thr / 8 waves; i-tile 16, j-tile 32, slabs
// jt ≡ s mod 4 (≤16 balanced iters). All LDS ops b64/b128, ≤2-way conflicts.
//  scores: wave w -> f = 4*(w&3)..+3 at j-chunk jh=w>>2; E packed half4 over f.
//  mix:    Pm[j,e] = E[j,f]·Wpost^T (A=E b64 read, B=W in regs); half4-over-j writes.
//  PV:     wave w -> e={2w,2w+1}; A=Pm b128 read (conflict-free), K=32 MFMA.
// Loop: [mix; bar; PV + scores(t+1); bar].  LDS 39.3 KB -> 2 blocks/CU.
// ---------------------------------------------------------------------------
__global__ __launch_bounds__(512,4) void attend_kernel(const Hh* __restrict__ qb,
    const Hh* __restrict__ kb, const Hh* __restrict__ vt2,
    const float* __restrict__ lacc_g, const float* __restrict__ Wpost,
    float* __restrict__ out)
{
    __shared__ Hh Ebuf[32*EB_JS];   // 20736 B
    __shared__ Hh Pm[16*PM_ES];     // 18560 B

    int bid = blockIdx.x;
    int s = bid & 3;
    int idx = 255 - (bid >> 2);
    int b = idx & 1, it = idx >> 1;          // it 0..127
    int jtmax = it >> 1;                     // last 32-j tile
    if (s > jtmax) return;
    int i0 = it * 16;

    int tid = threadIdx.x;
    int lane = tid & 63, w = tid >> 6;
    int qd = lane >> 4, c = lane & 15;

    // ---- scores role: wave w -> f-group fg=w&3 (f=4fg..4fg+3), j-chunk jh=w>>2
    int fg = w & 3, jh = w >> 2;
    half8 aq[4][2];
    float lgr[4][4];
    #pragma unroll
    for (int ff=0; ff<4; ff++) {
        int f = 4*fg + ff;
        const Hh* qr = qb + (size_t)((b*16+f)*N_ + i0 + c)*64 + qd*8;
        aq[ff][0] = *(const half8*)qr;
        aq[ff][1] = *(const half8*)(qr+32);
        #pragma unroll
        for (int r=0; r<4; r++)
            lgr[ff][r] = __builtin_amdgcn_logf(
                lacc_g[(size_t)(b*16+f)*N_ + i0 + qd*4 + r]);
    }
    // ---- mix role: wave w -> jh2=w&1, i in [4*(w>>1), +4)
    int jh2 = w & 1, ib = 4*(w>>1);
    half4 wf;   // B[k=f=qd*4+z][n=e=c] = Wpost[e][f]
    #pragma unroll
    for (int z=0; z<4; z++) wf[z] = (Hh)Wpost[c*16 + qd*4 + z];

    float4v acc[2][4];
    #pragma unroll
    for (int el=0; el<2; el++) for (int nc=0; nc<4; nc++)
        acc[el][nc] = (float4v){0.f,0.f,0.f,0.f};

    auto scores = [&](int jt) {
        int jc = jt*32 + jh*16;
        float4v sv[4];
        #pragma unroll
        for (int ff=0; ff<4; ff++) {
            int f = 4*fg + ff;
            const Hh* kr = kb + (size_t)((b*16+f)*N_ + jc + c)*64 + qd*8;
            half8 b0 = *(const half8*)kr;
            half8 b1 = *(const half8*)(kr+32);
            float4v t = {0.f,0.f,0.f,0.f};
            t = __builtin_amdgcn_mfma_f32_16x16x32_f16(aq[ff][0], b0, t, 0,0,0);
            t = __builtin_amdgcn_mfma_f32_16x16x32_f16(aq[ff][1], b1, t, 0,0,0);
            sv[ff] = t;
        }
        int j = jc + c;
        #pragma unroll
        for (int r=0; r<4; r++) {
            int i = i0 + qd*4 + r;
            half4 h;
            #pragma unroll
            for (int ff=0; ff<4; ff++)
                h[ff] = (Hh)((j <= i) ? __builtin_amdgcn_exp2f(sv[ff][r]*C1 - lgr[ff][r]) : 0.f);
            *(half4*)&Ebuf[(jh*16+c)*EB_JS + (qd*4+r)*EB_IS + fg*4] = h;
        }
    };

    scores(s);
    __syncthreads();

    for (int jt = s; jt <= jtmax; jt += 4) {
        // ---- head mix: Pm[j,e] for this wave's (jh2, i-quad) ----
        #pragma unroll
        for (int ii=0; ii<4; ii++) {
            int i = ib + ii;
            half4 ef = *(const half4*)&Ebuf[(jh2*16+c)*EB_JS + i*EB_IS + qd*4];
            float4v cc = {0.f,0.f,0.f,0.f};
            cc = __builtin_amdgcn_mfma_f32_16x16x16f16(ef, wf, cc, 0,0,0);
            // D[m=j=qd*4+r][n=e=c] -> pack half4 over j
            half4 hv;
            #pragma unroll
            for (int r=0; r<4; r++) hv[r] = (Hh)cc[r];
            *(half4*)&Pm[c*PM_ES + i*PM_IS + jh2*16 + qd*4] = hv;
        }
        __syncthreads();
        // ---- PV(jt), overlapped with scores(jt+4) ----
        #pragma unroll
        for (int el=0; el<2; el++) {
            int e = 2*w + el;
            half8 pa = *(const half8*)&Pm[e*PM_ES + c*PM_IS + qd*8];
            #pragma unroll
            for (int nc=0; nc<4; nc++) {
                const Hh* vr = vt2 + (size_t)((b*16+e)*64 + jt)*2048 + (nc*16+c)*32 + qd*8;
                half8 vb = *(const half8*)vr;
                acc[el][nc] = __builtin_amdgcn_mfma_f32_16x16x32_f16(pa, vb, acc[el][nc], 0,0,0);
            }
        }
        if (jt + 4 <= jtmax) scores(jt + 4);
        __syncthreads();
    }

    // ---- accumulate partial O: D[m=i][n=d], row=i0+qd*4+r, col d=nc*16+c ----
    #pragma unroll
    for (int el=0; el<2; el++) {
        int e = 2*w + el;
        #pragma unroll
        for (int nc=0; nc<4; nc++) {
            #pragma unroll
            for (int r=0; r<4; r++)
                unsafeAtomicAdd(&out[(size_t)((b*16+e)*N_ + i0 + qd*4 + r)*64 + nc*16 + c],
                                acc[el][nc][r]);
        }
    }
}

extern "C" void kernel_launch(void* const* d_in, const int* in_sizes, int n_in,
                              void* d_out, int out_size, void* d_ws, size_t ws_size,
                              hipStream_t stream) {
    const float* q     = (const float*)d_in[0];
    const float* k     = (const float*)d_in[1];
    const float* v     = (const float*)d_in[2];
    const float* Wpre  = (const float*)d_in[3];
    const float* Wpost = (const float*)d_in[4];
    float* out = (float*)d_out;

    size_t tsz = (size_t)B_*H_*N_*D_;       // 4 Mi halves = 8 MB each
    Hh* qb = (Hh*)d_ws;
    Hh* kb = qb + tsz;
    Hh* vt2 = kb + tsz;
    float* lacc = (float*)(vt2 + tsz);      // 24 MB offset, 256 KB

    hipMemsetAsync(lacc, 0, (size_t)B_*H_*N_*sizeof(float), stream);
    hipMemsetAsync(out, 0, (size_t)out_size*sizeof(float), stream);
    prep_kernel<<<768, 256, 0, stream>>>(q, k, v, Wpre, qb, kb, vt2);
    denom_kernel<<<1024, 512, 0, stream>>>(qb, kb, lacc);
    attend_kernel<<<1024, 512, 0, stream>>>(qb, kb, vt2, lacc, Wpost, out);
}